// Round 7
// baseline (226.191 us; speedup 1.0000x reference)
//
#include <hip/hip_runtime.h>

// TextCNN: B=128, S=512, E=300, H=64, k_i = i/2+2 in [2,33].
// Virtual-im2col bf16 MFMA (16x16x32 — HW-verified fragment layouts), fused gather,
// E-split LDS staging, wave = (M-half, j-parity) so each A-frag feeds 4 groups.
//   Grid: 128 b x 6 slices (96 rows) = 768 blocks, 42 KB LDS -> 3 blk/CU, 3 waves/SIMD.
//   Wave (p,q): p = rows p*48..+47 (3 tiles), q = j parity (K-split, LDS-reduced).
//   Groups g0..g3 = filters 0..15/16..31/32..47/48..63, caps j<9/17/25/33.
//   wsB prepacked [half][group][j*5+u] B-frag order; group bases {0,45,130,255}.
//   EPILOGUE FIX vs r6: mx accumulates across ALL 3 tiles before the single
//   wsF write (r5/r6 wrote inside the t-loop -> only last tile's max survived).
// ws: [0, 860KB) wsB bf16 | [1MB, +384KB) wsF f32 (128*64*12).

#define SS     512
#define EE     300
#define HH     64
#define LP     168          // LDS half-row pitch in elems (336 B)
#define HALFSZ 215040       // wsB elems per E-half (420 steps * 512)

typedef __attribute__((ext_vector_type(8))) short bf16x8;
typedef __attribute__((ext_vector_type(4))) float f32x4;

__device__ __forceinline__ unsigned short f2bf(float f) {
    unsigned u = __float_as_uint(f);
    unsigned r = ((u >> 16) & 1u) + 0x7FFFu;   // RNE
    return (unsigned short)((u + r) >> 16);
}

// ---- Kernel 1: repack Wconv (f32 [64][33][300]) -> wsB bf16, 16x16x32 B-frag order.
// (verbatim from round 4 — verified)
__global__ __launch_bounds__(256) void prep_weights(const float* __restrict__ Wconv,
                                                    unsigned short* __restrict__ wsB) {
    int idx = blockIdx.x * 256 + threadIdx.x;      // < 430080
    int r    = idx & 7;
    int lane = (idx >> 3) & 63;
    int gs   = idx >> 9;                           // < 840
    int h    = gs / 420;
    int ww   = gs - h * 420;
    int g, t;
    if      (ww < 45)  { g = 0; t = ww;       }
    else if (ww < 130) { g = 1; t = ww - 45;  }
    else if (ww < 255) { g = 2; t = ww - 130; }
    else               { g = 3; t = ww - 255; }
    int j = t / 5, u = t - j * 5;
    int i  = g * 16 + (lane & 15);
    int ki = i / 2 + 2;
    int kk = (lane >> 4) * 8 + r;
    int e  = h * 160 + u * 32 + kk;
    float v = 0.f;
    if (e < EE && j < ki) v = Wconv[(i * 33 + j) * EE + e];
    wsB[idx] = f2bf(v);
}

#define MFMA(A, Bf, C) __builtin_amdgcn_mfma_f32_16x16x32_bf16((A), (Bf), (C), 0, 0, 0)

template<int NG>   // groups active counted from the top: g3 always, then g2, g1, g0
__device__ __forceinline__ void stepJ(const unsigned short* lb, int j,
                                      const unsigned short* __restrict__ bp,
                                      f32x4 acc[3][4]) {
    #pragma unroll
    for (int u = 0; u < 5; ++u) {
        const unsigned short* lr = lb + j * LP + u * 32;
        bf16x8 a0 = *(const bf16x8*)(lr);
        bf16x8 a1 = *(const bf16x8*)(lr + 16 * LP);
        bf16x8 a2 = *(const bf16x8*)(lr + 32 * LP);
        int f = j * 5 + u;
        bf16x8 b3 = *(const bf16x8*)(bp + (255 + f) * 512);
        acc[0][3] = MFMA(a0, b3, acc[0][3]);
        acc[1][3] = MFMA(a1, b3, acc[1][3]);
        acc[2][3] = MFMA(a2, b3, acc[2][3]);
        if (NG >= 2) {
            bf16x8 b2 = *(const bf16x8*)(bp + (130 + f) * 512);
            acc[0][2] = MFMA(a0, b2, acc[0][2]);
            acc[1][2] = MFMA(a1, b2, acc[1][2]);
            acc[2][2] = MFMA(a2, b2, acc[2][2]);
        }
        if (NG >= 3) {
            bf16x8 b1 = *(const bf16x8*)(bp + (45 + f) * 512);
            acc[0][1] = MFMA(a0, b1, acc[0][1]);
            acc[1][1] = MFMA(a1, b1, acc[1][1]);
            acc[2][1] = MFMA(a2, b1, acc[2][1]);
        }
        if (NG >= 4) {
            bf16x8 b0 = *(const bf16x8*)(bp + f * 512);
            acc[0][0] = MFMA(a0, b0, acc[0][0]);
            acc[1][0] = MFMA(a1, b0, acc[1][0]);
            acc[2][0] = MFMA(a2, b0, acc[2][0]);
        }
    }
}

// ---- Kernel 2: fused gather + GEMM + tanh + masked max. 768 blocks x 256 thr.
__global__ __launch_bounds__(256, 3) void conv_fused(const int* __restrict__ x,
                                                     const float* __restrict__ emb,
                                                     const unsigned short* __restrict__ wsB,
                                                     const float* __restrict__ bconv,
                                                     float* __restrict__ wsF) {
    __shared__ __align__(16) unsigned short At[128 * LP];   // 42 KB

    int b     = blockIdx.x / 6;
    int slice = blockIdx.x - b * 6;
    int t0    = slice * 96;

    int lane = threadIdx.x & 63;
    int w    = threadIdx.x >> 6;
    int p    = w >> 1;                 // M-half: rows p*48 .. p*48+47
    int q    = w & 1;                  // j parity (K-split)
    int m = lane & 15, q16 = lane >> 4;

    f32x4 acc[3][4] = {};              // [tile][group]
    const unsigned short* lb = At + (p * 48 + m) * LP + q16 * 8;

    for (int eh = 0; eh < 2; ++eh) {
        if (eh) __syncthreads();
        // Stage 128 half-rows (96 + 32 halo), f32 -> bf16, zero-padded.
        #pragma unroll
        for (int it = 0; it < 10; ++it) {
            int idx = threadIdx.x + it * 256;      // < 2560 = 128*20
            int rr = idx / 20, c = idx - rr * 20;
            int srow = t0 + rr;
            bf16x8 v = {0, 0, 0, 0, 0, 0, 0, 0};
            if (srow < SS) {
                int tok = x[b * SS + srow];
                const float* ep = emb + (long)tok * EE + eh * 160 + c * 8;
                if (eh == 0 || c < 17) {
                    float4 f0 = ((const float4*)ep)[0];
                    float4 f1 = ((const float4*)ep)[1];
                    v[0] = f2bf(f0.x); v[1] = f2bf(f0.y); v[2] = f2bf(f0.z); v[3] = f2bf(f0.w);
                    v[4] = f2bf(f1.x); v[5] = f2bf(f1.y); v[6] = f2bf(f1.z); v[7] = f2bf(f1.w);
                } else if (c == 17) {              // elems 296..299
                    float4 f0 = ((const float4*)ep)[0];
                    v[0] = f2bf(f0.x); v[1] = f2bf(f0.y); v[2] = f2bf(f0.z); v[3] = f2bf(f0.w);
                }
            }
            *(bf16x8*)&At[rr * LP + c * 8] = v;
        }
        __syncthreads();

        const unsigned short* bp = wsB + eh * HALFSZ + lane * 8;
        #pragma unroll 1
        for (int j = q;      j < 9;  j += 2) stepJ<4>(lb, j, bp, acc);
        #pragma unroll 1
        for (int j = 10 - q; j < 17; j += 2) stepJ<3>(lb, j, bp, acc);
        #pragma unroll 1
        for (int j = 18 - q; j < 25; j += 2) stepJ<2>(lb, j, bp, acc);
        #pragma unroll 1
        for (int j = 26 - q; j < 33; j += 2) stepJ<1>(lb, j, bp, acc);
    }

    // Cross-wave K-reduction (q=1 partials -> q=0) via LDS, lane-contiguous.
    __syncthreads();
    float* red = (float*)At;
    if (q == 1) {
        #pragma unroll
        for (int t = 0; t < 3; ++t)
            #pragma unroll
            for (int g = 0; g < 4; ++g)
                #pragma unroll
                for (int r = 0; r < 4; ++r)
                    red[p * 3072 + ((t * 4 + g) * 4 + r) * 64 + lane] = acc[t][g][r];
    }
    __syncthreads();
    if (q == 0) {
        #pragma unroll
        for (int t = 0; t < 3; ++t)
            #pragma unroll
            for (int g = 0; g < 4; ++g)
                #pragma unroll
                for (int r = 0; r < 4; ++r)
                    acc[t][g][r] += red[p * 3072 + ((t * 4 + g) * 4 + r) * 64 + lane];

        // Epilogue: C/D col = lane&15, row = q16*4 + reg (verified layout).
        // g outer, t inner: ONE wsF write per (g, slice, p), max over all 3 tiles.
        #pragma unroll
        for (int g = 0; g < 4; ++g) {
            int i  = g * 16 + m;
            int ki = i / 2 + 2;
            int tmax = SS - ki;
            float bc = bconv[i];
            float mx = -3.0e38f;
            #pragma unroll
            for (int t = 0; t < 3; ++t) {
                int tb = t0 + p * 48 + t * 16 + q16 * 4;
                #pragma unroll
                for (int r = 0; r < 4; ++r) {
                    float v = tanhf(acc[t][g][r] + bc);
                    if (tb + r <= tmax) mx = fmaxf(mx, v);
                }
            }
            mx = fmaxf(mx, __shfl_xor(mx, 16));
            mx = fmaxf(mx, __shfl_xor(mx, 32));
            if (q16 == 0) wsF[(b * HH + i) * 12 + slice * 2 + p] = mx;
        }
    }
}

// ---- Kernel 3: max over 12 partials, linear, sigmoid. 128 blocks x 64 thr.
__global__ __launch_bounds__(64) void final_linear(const float* __restrict__ wsF,
                                                   const float* __restrict__ Wlin,
                                                   const float* __restrict__ blin,
                                                   float* __restrict__ out) {
    int b = blockIdx.x;
    int i = threadIdx.x;
    const float4* pp = (const float4*)(wsF + (b * HH + i) * 12);
    float4 f0 = pp[0], f1 = pp[1], f2 = pp[2];
    float mx = fmaxf(fmaxf(fmaxf(f0.x, f0.y), fmaxf(f0.z, f0.w)),
               fmaxf(fmaxf(fmaxf(f1.x, f1.y), fmaxf(f1.z, f1.w)),
                     fmaxf(fmaxf(f2.x, f2.y), fmaxf(f2.z, f2.w))));
    float v = mx * Wlin[i];
    #pragma unroll
    for (int off = 1; off < 64; off <<= 1) v += __shfl_xor(v, off);
    if (i == 0) out[b] = 1.0f / (1.0f + expf(-(v + blin[0])));
}

extern "C" void kernel_launch(void* const* d_in, const int* in_sizes, int n_in,
                              void* d_out, int out_size, void* d_ws, size_t ws_size,
                              hipStream_t stream) {
    const int*   x     = (const int*)d_in[0];
    const float* emb   = (const float*)d_in[1];
    const float* Wconv = (const float*)d_in[2];
    const float* bconv = (const float*)d_in[3];
    const float* Wlin  = (const float*)d_in[4];
    const float* blin  = (const float*)d_in[5];
    float* out = (float*)d_out;

    unsigned short* wsB = (unsigned short*)d_ws;
    float*          wsF = (float*)((char*)d_ws + (1u << 20));

    prep_weights<<<1680, 256, 0, stream>>>(Wconv, wsB);
    conv_fused<<<768, 256, 0, stream>>>(x, emb, wsB, bconv, wsF);
    final_linear<<<128, 64, 0, stream>>>(wsF, Wlin, blin, out);
}